// Round 1
// baseline (234.206 us; speedup 1.0000x reference)
//
#include <hip/hip_runtime.h>

// Inverse 2D Haar wavelet (2-tap, stride-2 conv_transpose, depthwise).
// x:   [B=8, 4*C=256, H=128, W=128] fp32, subbands [LL | HL | LH | HH]
// out: [B=8, C=64, 2H=256, 2W=256] fp32
//
//   out[2h  ][2w  ] = 0.5*(LL + LH + HL + HH)
//   out[2h  ][2w+1] = 0.5*(LL - LH + HL - HH)
//   out[2h+1][2w  ] = 0.5*(LL + LH - HL - HH)
//   out[2h+1][2w+1] = 0.5*(LL - LH - HL + HH)
//
// R4: widen input loads 8B/lane (dwordx2) -> 16B/lane (dwordx4).
// Each thread: 4 input cols per subband -> 2 output rows x 8 cols.
// Halves thread count (4.2M -> 2.1M), halves VMEM instructions per byte.
// All index math 32-bit (max elem offset 33.5M << 2^31) so loads get the
// saddr + 32-bit voffset form. Nontemporal load/store retained (R3 win:
// non-allocating streams don't evict the harness poison's dirty MALL lines).

typedef float vf4 __attribute__((ext_vector_type(4)));

__global__ __launch_bounds__(256) void iwt_haar_kernel(const float* __restrict__ x,
                                                       float* __restrict__ out) {
    constexpr int W = 128, H = 128, C = 64;
    constexpr int W4 = W / 4;            // 32 vf4 per input row
    constexpr int PLANE = H * W;         // 16384
    constexpr int CP = C * PLANE;        // 1,048,576 floats = 4 MiB subband-group stride

    const int idx = blockIdx.x * blockDim.x + threadIdx.x;
    const int w4 = idx & (W4 - 1);           // 5 bits
    const int h  = (idx >> 5) & (H - 1);     // 7 bits
    const int c  = (idx >> 12) & (C - 1);    // 6 bits
    const int b  = idx >> 18;                // 3 bits

    const float* p = x + (b * 4 * C + c) * PLANE + h * W + w4 * 4;
    const vf4 ll = __builtin_nontemporal_load((const vf4*)(p));
    const vf4 hl = __builtin_nontemporal_load((const vf4*)(p + 1 * CP));
    const vf4 lh = __builtin_nontemporal_load((const vf4*)(p + 2 * CP));
    const vf4 hh = __builtin_nontemporal_load((const vf4*)(p + 3 * CP));

    // Per input column j: width-pass butterfly (s/d), then height-pass
    // butterfly interleaved into even/odd output columns of rows 2h, 2h+1.
    vf4 r0a, r0b, r1a, r1b;
    float s0, d0, s1, d1;

    s0 = ll.x + lh.x; d0 = ll.x - lh.x; s1 = hl.x + hh.x; d1 = hl.x - hh.x;
    r0a.x = 0.5f * (s0 + s1); r0a.y = 0.5f * (d0 + d1);
    r1a.x = 0.5f * (s0 - s1); r1a.y = 0.5f * (d0 - d1);

    s0 = ll.y + lh.y; d0 = ll.y - lh.y; s1 = hl.y + hh.y; d1 = hl.y - hh.y;
    r0a.z = 0.5f * (s0 + s1); r0a.w = 0.5f * (d0 + d1);
    r1a.z = 0.5f * (s0 - s1); r1a.w = 0.5f * (d0 - d1);

    s0 = ll.z + lh.z; d0 = ll.z - lh.z; s1 = hl.z + hh.z; d1 = hl.z - hh.z;
    r0b.x = 0.5f * (s0 + s1); r0b.y = 0.5f * (d0 + d1);
    r1b.x = 0.5f * (s0 - s1); r1b.y = 0.5f * (d0 - d1);

    s0 = ll.w + lh.w; d0 = ll.w - lh.w; s1 = hl.w + hh.w; d1 = hl.w - hh.w;
    r0b.z = 0.5f * (s0 + s1); r0b.w = 0.5f * (d0 + d1);
    r1b.z = 0.5f * (s0 - s1); r1b.w = 0.5f * (d0 - d1);

    constexpr int OW = 2 * W;            // 256
    constexpr int OPLANE = 2 * H * OW;   // 65536
    float* q = out + (b * C + c) * OPLANE + (2 * h) * OW + w4 * 8;
    __builtin_nontemporal_store(r0a, (vf4*)(q));
    __builtin_nontemporal_store(r0b, (vf4*)(q + 4));
    __builtin_nontemporal_store(r1a, (vf4*)(q + OW));
    __builtin_nontemporal_store(r1b, (vf4*)(q + OW + 4));
}

extern "C" void kernel_launch(void* const* d_in, const int* in_sizes, int n_in,
                              void* d_out, int out_size, void* d_ws, size_t ws_size,
                              hipStream_t stream) {
    const float* x = (const float*)d_in[0];
    float* out = (float*)d_out;

    // total threads = 8 * 64 * 128 * 32 = 2,097,152
    const int total = 8 * 64 * 128 * 32;
    const int block = 256;
    const int grid = total / block;  // 8192
    iwt_haar_kernel<<<grid, block, 0, stream>>>(x, out);
}

// Round 2
// 219.367 us; speedup vs baseline: 1.0676x; 1.0676x over previous
//
#include <hip/hip_runtime.h>

// Inverse 2D Haar wavelet (2-tap, stride-2 conv_transpose, depthwise).
// x:   [B=8, 4*C=256, H=128, W=128] fp32, subbands [LL | HL | LH | HH]
// out: [B=8, C=64, 2H=256, 2W=256] fp32
//
//   out[2h  ][2w  ] = 0.5*(LL + LH + HL + HH)
//   out[2h  ][2w+1] = 0.5*(LL - LH + HL - HH)
//   out[2h+1][2w  ] = 0.5*(LL + LH - HL - HH)
//   out[2h+1][2w+1] = 0.5*(LL - LH - HL + HH)
//
// R5: R4's 16B/lane loads regressed because the stores became lane-gapped
// (each lane owns 8 output cols -> two vf4 stores at 32B lane-stride; each
// nt store instruction writes only alternating 16B chunks of the wave's
// span -> partial-line nontemporal writes). Fix: stage the block's 16x256
// output tile in LDS, then re-read so every nt store instruction is a
// wave-contiguous 1KiB segment. Keeps 16B nt loads AND 16B contiguous nt
// stores. LDS traffic (2x 16KiB/block) is noise vs HBM.

typedef float vf4 __attribute__((ext_vector_type(4)));

__global__ __launch_bounds__(256) void iwt_haar_kernel(const float* __restrict__ x,
                                                       float* __restrict__ out) {
    constexpr int W = 128, H = 128, C = 64;
    constexpr int PLANE = H * W;          // 16384
    constexpr int CP = C * PLANE;         // 1,048,576 floats (4 MiB subband stride)
    constexpr int OW = 2 * W;             // 256
    constexpr int OPLANE = 2 * H * OW;    // 65536
    constexpr int LSTRIDE = 260;          // 256 + 4 pad floats; keeps rows 16B-aligned

    // Block geometry: 256 threads = w4(32) x r(8 input rows).
    // Grid 8192 = hg(16) x c(64) x b(8).
    const int tid = threadIdx.x;
    const int u = tid & 31;        // vf4 index within input row (4 cols each)
    const int r = tid >> 5;        // input row within block [0,8)

    const int blk = blockIdx.x;
    const int hg = blk & 15;             // input-row octet
    const int c  = (blk >> 4) & (C - 1); // channel
    const int b  = blk >> 10;            // batch

    const int h = hg * 8 + r;

    const float* p = x + (b * 4 * C + c) * PLANE + h * W + u * 4;
    const vf4 ll = __builtin_nontemporal_load((const vf4*)(p));
    const vf4 hl = __builtin_nontemporal_load((const vf4*)(p + 1 * CP));
    const vf4 lh = __builtin_nontemporal_load((const vf4*)(p + 2 * CP));
    const vf4 hh = __builtin_nontemporal_load((const vf4*)(p + 3 * CP));

    // Width-pass butterfly (s/d) per input col, then height-pass butterfly
    // interleaved into even/odd output columns of rows 2h, 2h+1.
    vf4 r0a, r0b, r1a, r1b;
    float s0, d0, s1, d1;

    s0 = ll.x + lh.x; d0 = ll.x - lh.x; s1 = hl.x + hh.x; d1 = hl.x - hh.x;
    r0a.x = 0.5f * (s0 + s1); r0a.y = 0.5f * (d0 + d1);
    r1a.x = 0.5f * (s0 - s1); r1a.y = 0.5f * (d0 - d1);

    s0 = ll.y + lh.y; d0 = ll.y - lh.y; s1 = hl.y + hh.y; d1 = hl.y - hh.y;
    r0a.z = 0.5f * (s0 + s1); r0a.w = 0.5f * (d0 + d1);
    r1a.z = 0.5f * (s0 - s1); r1a.w = 0.5f * (d0 - d1);

    s0 = ll.z + lh.z; d0 = ll.z - lh.z; s1 = hl.z + hh.z; d1 = hl.z - hh.z;
    r0b.x = 0.5f * (s0 + s1); r0b.y = 0.5f * (d0 + d1);
    r1b.x = 0.5f * (s0 - s1); r1b.y = 0.5f * (d0 - d1);

    s0 = ll.w + lh.w; d0 = ll.w - lh.w; s1 = hl.w + hh.w; d1 = hl.w - hh.w;
    r0b.z = 0.5f * (s0 + s1); r0b.w = 0.5f * (d0 + d1);
    r1b.z = 0.5f * (s0 - s1); r1b.w = 0.5f * (d0 - d1);

    // Stage the block's 16x256 output tile in LDS.
    __shared__ __attribute__((aligned(16))) float lds[16][LSTRIDE];
    *(vf4*)&lds[2 * r    ][8 * u    ] = r0a;
    *(vf4*)&lds[2 * r    ][8 * u + 4] = r0b;
    *(vf4*)&lds[2 * r + 1][8 * u    ] = r1a;
    *(vf4*)&lds[2 * r + 1][8 * u + 4] = r1b;

    __syncthreads();

    // Re-read so each nt store instruction is wave-contiguous (64 lanes x
    // consecutive 16B = 1KiB). 16 rows x 64 vf4-chunks = 1024 chunks; each
    // thread stores 4: chunk = tid + 256*i.
    float* qbase = out + (b * C + c) * OPLANE + (hg * 16) * OW;
#pragma unroll
    for (int i = 0; i < 4; ++i) {
        const int chunk = tid + 256 * i;
        const int row = chunk >> 6;          // [0,16)
        const int col4 = chunk & 63;         // vf4 index within output row
        const vf4 v = *(const vf4*)&lds[row][col4 * 4];
        __builtin_nontemporal_store(v, (vf4*)(qbase + row * OW + col4 * 4));
    }
}

extern "C" void kernel_launch(void* const* d_in, const int* in_sizes, int n_in,
                              void* d_out, int out_size, void* d_ws, size_t ws_size,
                              hipStream_t stream) {
    const float* x = (const float*)d_in[0];
    float* out = (float*)d_out;

    // total threads = 8 * 64 * 128 * 32 = 2,097,152
    const int total = 8 * 64 * 128 * 32;
    const int block = 256;
    const int grid = total / block;  // 8192 = 16 (h-octets) x 64 (c) x 8 (b)
    iwt_haar_kernel<<<grid, block, 0, stream>>>(x, out);
}